// Round 13
// baseline (250.053 us; speedup 1.0000x reference)
//
#include <hip/hip_runtime.h>

// ---------------------------------------------------------------------------
// GraphSAGE (2-layer, mean aggregator), N=100000, E=1600000, D=128, fp32 out.
// R12: GEMM occupancy fix. R6-form wave (B 64 + A-dbuf 64 VGPR) sat at ~150+
// VGPR -> 2-3 waves/SIMD, grid 782 -> ~3 blocks/CU: too few in-flight loads.
// Now: single A buffer, __launch_bounds__(256,4) (VGPR<=128 -> 4 waves/SIMD),
// 64-node blocks (grid 1564 -> ~6/CU) -> ~16 waves/CU, 2x in-flight loads.
// 2-o-tile-per-wave reuse kept (R10 showed 1 o-tile/wave regresses).
// agg = R11 paired-gather form (best measured); CSR pipeline unchanged.
// ---------------------------------------------------------------------------

typedef unsigned int uint;
typedef unsigned short ushort;
using short8 = __attribute__((ext_vector_type(8))) short;
using f32x4  = __attribute__((ext_vector_type(4))) float;

__device__ __forceinline__ float bflo(uint u) { return __uint_as_float(u << 16); }
__device__ __forceinline__ float bfhi(uint u) { return __uint_as_float(u & 0xffff0000u); }
__device__ __forceinline__ ushort f2bf(float f) {
  uint u = __float_as_uint(f);
  return (ushort)((u + 0x7fffu + ((u >> 16) & 1u)) >> 16);
}

#define EPB 4096        // edges per partition block
#define NBKT_MAX 512    // buckets of 256 nodes; N<=131072
#define SLAB_CAP 5120   // slab capacity per bucket

__global__ __launch_bounds__(256) void f32_to_bf16_kernel(
    const float* __restrict__ in, ushort* __restrict__ out, int n4) {
  int i = blockIdx.x * 256 + threadIdx.x;
  if (i >= n4) return;
  float4 v = ((const float4*)in)[i];
  ushort4 r;
  r.x = f2bf(v.x); r.y = f2bf(v.y); r.z = f2bf(v.z); r.w = f2bf(v.w);
  ((ushort4*)out)[i] = r;
}

// One launch converts all 4 weight matrices (blockIdx.y selects matrix).
__global__ __launch_bounds__(256) void w_to_bf16_kernel(
    const float* __restrict__ w0, const float* __restrict__ w1,
    const float* __restrict__ w2, const float* __restrict__ w3,
    ushort* __restrict__ o0, ushort* __restrict__ o1,
    ushort* __restrict__ o2, ushort* __restrict__ o3, int n4) {
  int i = blockIdx.x * 256 + threadIdx.x;
  if (i >= n4) return;
  const float* in = (blockIdx.y == 0) ? w0 : (blockIdx.y == 1) ? w1
                    : (blockIdx.y == 2) ? w2 : w3;
  ushort* out = (blockIdx.y == 0) ? o0 : (blockIdx.y == 1) ? o1
                : (blockIdx.y == 2) ? o2 : o3;
  float4 v = ((const float4*)in)[i];
  ushort4 r;
  r.x = f2bf(v.x); r.y = f2bf(v.y); r.z = f2bf(v.z); r.w = f2bf(v.w);
  ((ushort4*)out)[i] = r;
}

__global__ __launch_bounds__(256) void partition_kernel(
    const int* __restrict__ src, const int* __restrict__ dst,
    int* __restrict__ bktcnt, uint* __restrict__ gpart, int E, int nbkt) {
  __shared__ uint staged[EPB];
  __shared__ ushort stagedb[EPB];     // bucket id per staged slot
  __shared__ int hist[NBKT_MAX];
  __shared__ int scanex[NBKT_MAX];
  __shared__ int lcur[NBKT_MAX];
  __shared__ int gbase[NBKT_MAX];
  __shared__ int s2[256];
  const int t = threadIdx.x;
  const int e0 = blockIdx.x * EPB;
  const int total = min(EPB, E - e0);

  hist[t] = 0; hist[t + 256] = 0;
  __syncthreads();

  int myb[16];
  uint myu[16];
#pragma unroll
  for (int q = 0; q < 16; ++q) {
    int e = e0 + q * 256 + t;
    if (e < E) {
      int s = src[e], d = dst[e];
      myb[q] = d >> 8;
      myu[q] = (uint)s | ((uint)(d & 255) << 24);
      atomicAdd(&hist[myb[q]], 1);
    } else {
      myb[q] = -1;
      myu[q] = 0;
    }
  }
  __syncthreads();

  int h0 = hist[2 * t], h1 = hist[2 * t + 1];
  s2[t] = h0 + h1;
  __syncthreads();
  for (int off = 1; off < 256; off <<= 1) {
    int v = (t >= off) ? s2[t - off] : 0;
    __syncthreads();
    s2[t] += v;
    __syncthreads();
  }
  int ex2 = s2[t] - (h0 + h1);
  scanex[2 * t] = ex2;
  scanex[2 * t + 1] = ex2 + h0;
  lcur[2 * t] = ex2;
  lcur[2 * t + 1] = ex2 + h0;
  __syncthreads();

#pragma unroll
  for (int q = 0; q < 2; ++q) {
    int b = t + q * 256;
    int c = hist[b];
    gbase[b] = (b < nbkt && c > 0)
                   ? (b * SLAB_CAP + atomicAdd(&bktcnt[b], c))
                   : 0;
  }

#pragma unroll
  for (int q = 0; q < 16; ++q) {
    if (myb[q] >= 0) {
      int p = atomicAdd(&lcur[myb[q]], 1);
      staged[p] = myu[q];
      stagedb[p] = (ushort)myb[q];
    }
  }
  __syncthreads();

  for (int i = t; i < total; i += 256) {
    int b = stagedb[i];
    gpart[gbase[b] + (i - scanex[b])] = staged[i];
  }
}

__global__ __launch_bounds__(512) void bucket_scan_kernel(
    const int* __restrict__ bktcnt, int* __restrict__ bucket_base,
    int* __restrict__ row_start, int nbkt, int n, int E) {
  __shared__ int sh[512];
  int t = threadIdx.x;
  int v = (t < nbkt) ? bktcnt[t] : 0;
  sh[t] = v;
  __syncthreads();
  for (int off = 1; off < 512; off <<= 1) {
    int u = (t >= off) ? sh[t - off] : 0;
    __syncthreads();
    sh[t] += u;
    __syncthreads();
  }
  if (t < nbkt) bucket_base[t] = sh[t] - v;
  if (t == 0) row_start[n] = E;
}

__global__ __launch_bounds__(256) void fine_fill_kernel(
    const uint* __restrict__ gpart, const int* __restrict__ bktcnt,
    const int* __restrict__ bucket_base, int* __restrict__ row_start,
    int* __restrict__ csr, int n) {
  __shared__ int hist[256];
  __shared__ int pfx[256];
  __shared__ int lcur[256];
  const int b = blockIdx.x;
  const int t = threadIdx.x;
  const int cnt = bktcnt[b];
  const uint* sl = gpart + (size_t)b * SLAB_CAP;
  hist[t] = 0;
  __syncthreads();
  for (int i = t; i < cnt; i += 256) atomicAdd(&hist[sl[i] >> 24], 1);
  __syncthreads();
  int h = hist[t];
  pfx[t] = h;
  __syncthreads();
  for (int off = 1; off < 256; off <<= 1) {
    int u = (t >= off) ? pfx[t - off] : 0;
    __syncthreads();
    pfx[t] += u;
    __syncthreads();
  }
  const int base = bucket_base[b] + pfx[t] - h;
  const int n0 = b << 8;
  if (n0 + t < n) row_start[n0 + t] = base;
  lcur[t] = base;
  __syncthreads();
  for (int i = t; i < cnt; i += 256) {
    uint u = sl[i];
    int p = atomicAdd(&lcur[u >> 24], 1);
    csr[p] = (int)(u & 0xFFFFFFu);
  }
}

// Half-wave (32 lanes) per node, PAIRED 16B/lane gather (R11 form, best):
// lanes 0-15 load edge j (uint4 = 8 dims), lanes 16-31 edge j+1; masked-fmaf;
// shfl_xor(16) cross-half reduce; lanes 0-15 write the 256B row.
__global__ __launch_bounds__(256) void aggregate_mean_bf16_kernel(
    const ushort* __restrict__ hb, const int* __restrict__ csr,
    const int* __restrict__ row_start, ushort* __restrict__ outb, int n) {
  int node = (blockIdx.x * 256 + threadIdx.x) >> 5;
  int lane = threadIdx.x & 31;
  if (node >= n) return;
  const int sub = lane >> 4;       // edge parity handled by this lane
  const int dlo = (lane & 15) * 8; // dims dlo..dlo+7
  int e0 = row_start[node], e1 = row_start[node + 1];
  float a0 = 0.f, a1 = 0.f, a2 = 0.f, a3 = 0.f;
  float a4 = 0.f, a5 = 0.f, a6 = 0.f, a7 = 0.f;
  if (e1 > e0) {
    const int elast = e1 - 1;
    for (int j0 = e0; j0 < e1; j0 += 8) {
      uint4 v[4];
      float m[4];
#pragma unroll
      for (int q = 0; q < 4; ++q) {
        int j = j0 + 2 * q + sub;
        int jc = (j <= elast) ? j : elast;
        int s = csr[jc];
        v[q] = *(const uint4*)(hb + (size_t)s * 128 + dlo);
        m[q] = (j <= elast) ? 1.0f : 0.0f;
      }
#pragma unroll
      for (int q = 0; q < 4; ++q) {
        a0 = fmaf(bflo(v[q].x), m[q], a0);
        a1 = fmaf(bfhi(v[q].x), m[q], a1);
        a2 = fmaf(bflo(v[q].y), m[q], a2);
        a3 = fmaf(bfhi(v[q].y), m[q], a3);
        a4 = fmaf(bflo(v[q].z), m[q], a4);
        a5 = fmaf(bfhi(v[q].z), m[q], a5);
        a6 = fmaf(bflo(v[q].w), m[q], a6);
        a7 = fmaf(bfhi(v[q].w), m[q], a7);
      }
    }
    a0 += __shfl_xor(a0, 16, 64);
    a1 += __shfl_xor(a1, 16, 64);
    a2 += __shfl_xor(a2, 16, 64);
    a3 += __shfl_xor(a3, 16, 64);
    a4 += __shfl_xor(a4, 16, 64);
    a5 += __shfl_xor(a5, 16, 64);
    a6 += __shfl_xor(a6, 16, 64);
    a7 += __shfl_xor(a7, 16, 64);
    float inv = 1.0f / (float)(e1 - e0);
    a0 *= inv; a1 *= inv; a2 *= inv; a3 *= inv;
    a4 *= inv; a5 *= inv; a6 *= inv; a7 *= inv;
  }
  if (lane < 16) {
    uint4 r;
    r.x = (uint)f2bf(a0) | ((uint)f2bf(a1) << 16);
    r.y = (uint)f2bf(a2) | ((uint)f2bf(a3) << 16);
    r.z = (uint)f2bf(a4) | ((uint)f2bf(a5) << 16);
    r.w = (uint)f2bf(a6) | ((uint)f2bf(a7) << 16);
    *(uint4*)(outb + (size_t)node * 128 + dlo) = r;
  }
}

// MFMA SAGE GEMM v4: 64 nodes x 128 outs per block, 4 waves; wave w owns
// o-tiles {w, w+4} (B-frags in regs whole kernel). Single A buffer + forced
// 4 waves/SIMD via __launch_bounds__(256,4): TLP (16 waves/CU) hides the
// load->MFMA dependency instead of a VGPR-hungry double buffer.
template <int RELU, int OUT_BF16>
__global__ __launch_bounds__(256, 4) void sage_gemm_mfma_kernel(
    const ushort* __restrict__ hs, const ushort* __restrict__ hn,
    const ushort* __restrict__ Wsb, const ushort* __restrict__ Wnb,
    const float* __restrict__ bias, void* __restrict__ out_, int n) {
  const int w = threadIdx.x >> 6;
  const int lane = threadIdx.x & 63;
  const int lr = lane & 15;
  const int lk = (lane >> 4) * 8;
  const int m0 = blockIdx.x * 64;
  if (m0 >= n) return;

  short8 bs[2][4], bn[2][4];
  float bv[2];
  int oc[2];
#pragma unroll
  for (int u = 0; u < 2; ++u) {
    oc[u] = (w + u * 4) * 16 + lr;
    const ushort* qs = Wsb + (size_t)oc[u] * 128 + lk;
    const ushort* qn = Wnb + (size_t)oc[u] * 128 + lk;
#pragma unroll
    for (int s = 0; s < 4; ++s) {
      bs[u][s] = *(const short8*)(qs + s * 32);
      bn[u][s] = *(const short8*)(qn + s * 32);
    }
    bv[u] = bias[oc[u]];
  }

  const int nmt = min(4, (n - m0 + 15) >> 4);
  for (int mt = 0; mt < nmt; ++mt) {
    // load A fragments (single buffer; latency covered by 16 waves/CU TLP)
    short8 as[4], an[4];
    {
      int arow = m0 + mt * 16 + lr;
      if (arow >= n) arow = n - 1;
      const ushort* ps = hs + (size_t)arow * 128 + lk;
      const ushort* pq = hn + (size_t)arow * 128 + lk;
#pragma unroll
      for (int s = 0; s < 4; ++s) {
        as[s] = *(const short8*)(ps + s * 32);
        an[s] = *(const short8*)(pq + s * 32);
      }
    }
    const int mbase = m0 + mt * 16 + (lane >> 4) * 4;
#pragma unroll
    for (int u = 0; u < 2; ++u) {
      f32x4 acc = {0.f, 0.f, 0.f, 0.f};
#pragma unroll
      for (int s = 0; s < 4; ++s)
        acc = __builtin_amdgcn_mfma_f32_16x16x32_bf16(as[s], bs[u][s], acc, 0, 0, 0);
#pragma unroll
      for (int s = 0; s < 4; ++s)
        acc = __builtin_amdgcn_mfma_f32_16x16x32_bf16(an[s], bn[u][s], acc, 0, 0, 0);
#pragma unroll
      for (int r = 0; r < 4; ++r) {
        int node = mbase + r;
        if (node < n) {
          float v = acc[r] + bv[u];
          if (RELU) v = fmaxf(v, 0.f);
          if (OUT_BF16)
            ((ushort*)out_)[(size_t)node * 128 + oc[u]] = f2bf(v);
          else
            ((float*)out_)[(size_t)node * 128 + oc[u]] = v;
        }
      }
    }
  }
}

extern "C" void kernel_launch(void* const* d_in, const int* in_sizes, int n_in,
                              void* d_out, int out_size, void* d_ws, size_t ws_size,
                              hipStream_t stream) {
  const float* x   = (const float*)d_in[0];
  const int*   src = (const int*)d_in[1];
  const int*   dst = (const int*)d_in[2];
  const float* Ws1 = (const float*)d_in[3];
  const float* Wn1 = (const float*)d_in[4];
  const float* b1  = (const float*)d_in[5];
  const float* Ws2 = (const float*)d_in[6];
  const float* Wn2 = (const float*)d_in[7];
  const float* b2  = (const float*)d_in[8];
  float* out = (float*)d_out;
  const int D = 128;
  const int N = in_sizes[0] / D;
  const int E = in_sizes[1];
  (void)n_in; (void)out_size; (void)ws_size;

  char* p = (char*)d_ws;
  auto carve = [&](size_t bytes) {
    char* r = p;
    p += (bytes + 255) & ~(size_t)255;
    return r;
  };
  int*    bktcnt      = (int*)carve(NBKT_MAX * 4);
  int*    bucket_base = (int*)carve(NBKT_MAX * 4);
  int*    row_start   = (int*)carve((size_t)(N + 1) * 4);
  uint*   gpart       = (uint*)carve((size_t)NBKT_MAX * SLAB_CAP * 4);
  int*    csr         = (int*)carve((size_t)E * 4);
  ushort* xb          = (ushort*)carve((size_t)N * D * 2);
  ushort* h1b         = (ushort*)carve((size_t)N * D * 2);
  ushort* hnb         = (ushort*)carve((size_t)N * D * 2);
  ushort* Wsb1        = (ushort*)carve((size_t)D * D * 2);
  ushort* Wnb1        = (ushort*)carve((size_t)D * D * 2);
  ushort* Wsb2        = (ushort*)carve((size_t)D * D * 2);
  ushort* Wnb2        = (ushort*)carve((size_t)D * D * 2);

  hipMemsetAsync(bktcnt, 0, NBKT_MAX * 4, stream);

  const int nbkt = (N + 255) >> 8;
  const int wq = D * D / 4;

  f32_to_bf16_kernel<<<(N * D / 4 + 255) / 256, 256, 0, stream>>>(x, xb, N * D / 4);
  {
    dim3 g((wq + 255) / 256, 4);
    w_to_bf16_kernel<<<g, 256, 0, stream>>>(Ws1, Wn1, Ws2, Wn2,
                                            Wsb1, Wnb1, Wsb2, Wnb2, wq);
  }

  partition_kernel<<<(E + EPB - 1) / EPB, 256, 0, stream>>>(src, dst, bktcnt, gpart, E, nbkt);
  bucket_scan_kernel<<<1, 512, 0, stream>>>(bktcnt, bucket_base, row_start, nbkt, N, E);
  fine_fill_kernel<<<nbkt, 256, 0, stream>>>(gpart, bktcnt, bucket_base, row_start, csr, N);

  const int gblocks = (N + 63) / 64;

  aggregate_mean_bf16_kernel<<<(N + 7) / 8, 256, 0, stream>>>(xb, csr, row_start, hnb, N);
  sage_gemm_mfma_kernel<1, 1><<<gblocks, 256, 0, stream>>>(
      xb, hnb, Wsb1, Wnb1, b1, h1b, N);

  aggregate_mean_bf16_kernel<<<(N + 7) / 8, 256, 0, stream>>>(h1b, csr, row_start, hnb, N);
  sage_gemm_mfma_kernel<0, 0><<<gblocks, 256, 0, stream>>>(
      h1b, hnb, Wsb2, Wnb2, b2, out, N);
}

// Round 14
// 235.787 us; speedup vs baseline: 1.0605x; 1.0605x over previous
//
#include <hip/hip_runtime.h>

// ---------------------------------------------------------------------------
// GraphSAGE (2-layer, mean aggregator), N=100000, E=1600000, D=128, fp32 out.
// R13: int8 gather path. Aggregate was byte-bound at the L3 random-service
// plateau (3.2 TB/s, FETCH 177MB pinned). Gather tables now int8 rows with
// per-node scale (12.8MB vs 25.6MB): q = rint(x*127/max|row|)+128; dequant
// folded into fmaf + one correction term. bf16 kept for GEMM A/B inputs.
// Workspace aliases: xq overlays h1b (dead until gemm1), h1q overlays xb
// (dead after gemm1). GEMM/partition/CSR unchanged from R12.
// ---------------------------------------------------------------------------

typedef unsigned int uint;
typedef unsigned short ushort;
typedef unsigned char uchar;
using short8 = __attribute__((ext_vector_type(8))) short;
using f32x4  = __attribute__((ext_vector_type(4))) float;

__device__ __forceinline__ float bflo(uint u) { return __uint_as_float(u << 16); }
__device__ __forceinline__ float bfhi(uint u) { return __uint_as_float(u & 0xffff0000u); }
__device__ __forceinline__ ushort f2bf(float f) {
  uint u = __float_as_uint(f);
  return (ushort)((u + 0x7fffu + ((u >> 16) & 1u)) >> 16);
}

#define EPB 4096        // edges per partition block
#define NBKT_MAX 512    // buckets of 256 nodes; N<=131072
#define SLAB_CAP 5120   // slab capacity per bucket

__global__ __launch_bounds__(256) void f32_to_bf16_kernel(
    const float* __restrict__ in, ushort* __restrict__ out, int n4) {
  int i = blockIdx.x * 256 + threadIdx.x;
  if (i >= n4) return;
  float4 v = ((const float4*)in)[i];
  ushort4 r;
  r.x = f2bf(v.x); r.y = f2bf(v.y); r.z = f2bf(v.z); r.w = f2bf(v.w);
  ((ushort4*)out)[i] = r;
}

// One launch converts all 4 weight matrices (blockIdx.y selects matrix).
__global__ __launch_bounds__(256) void w_to_bf16_kernel(
    const float* __restrict__ w0, const float* __restrict__ w1,
    const float* __restrict__ w2, const float* __restrict__ w3,
    ushort* __restrict__ o0, ushort* __restrict__ o1,
    ushort* __restrict__ o2, ushort* __restrict__ o3, int n4) {
  int i = blockIdx.x * 256 + threadIdx.x;
  if (i >= n4) return;
  const float* in = (blockIdx.y == 0) ? w0 : (blockIdx.y == 1) ? w1
                    : (blockIdx.y == 2) ? w2 : w3;
  ushort* out = (blockIdx.y == 0) ? o0 : (blockIdx.y == 1) ? o1
                : (blockIdx.y == 2) ? o2 : o3;
  float4 v = ((const float4*)in)[i];
  ushort4 r;
  r.x = f2bf(v.x); r.y = f2bf(v.y); r.z = f2bf(v.z); r.w = f2bf(v.w);
  ((ushort4*)out)[i] = r;
}

// Per-row symmetric int8 quantization (offset-128 unsigned storage).
// Half-wave (32 lanes) per node; lane holds 4 dims.
template <int IN_F32>
__global__ __launch_bounds__(256) void quant_rows_kernel(
    const void* __restrict__ in_, uchar* __restrict__ outq,
    float* __restrict__ scales, int n) {
  int node = (blockIdx.x * 256 + threadIdx.x) >> 5;
  int lane = threadIdx.x & 31;
  if (node >= n) return;
  float f[4];
  if (IN_F32) {
    float4 v = *(const float4*)((const float*)in_ + (size_t)node * 128 + lane * 4);
    f[0] = v.x; f[1] = v.y; f[2] = v.z; f[3] = v.w;
  } else {
    uint2 v = *(const uint2*)((const ushort*)in_ + (size_t)node * 128 + lane * 4);
    f[0] = bflo(v.x); f[1] = bfhi(v.x); f[2] = bflo(v.y); f[3] = bfhi(v.y);
  }
  float mx = fmaxf(fmaxf(fabsf(f[0]), fabsf(f[1])),
                   fmaxf(fabsf(f[2]), fabsf(f[3])));
#pragma unroll
  for (int off = 1; off < 32; off <<= 1) mx = fmaxf(mx, __shfl_xor(mx, off, 64));
  float inv = (mx > 0.f) ? 127.0f / mx : 0.f;
  uint q0 = (uint)(__float2int_rn(f[0] * inv) + 128);
  uint q1 = (uint)(__float2int_rn(f[1] * inv) + 128);
  uint q2 = (uint)(__float2int_rn(f[2] * inv) + 128);
  uint q3 = (uint)(__float2int_rn(f[3] * inv) + 128);
  uint packed = q0 | (q1 << 8) | (q2 << 16) | (q3 << 24);
  *(uint*)(outq + (size_t)node * 128 + lane * 4) = packed;
  if (lane == 0) scales[node] = (mx > 0.f) ? mx / 127.0f : 0.f;
}

__global__ __launch_bounds__(256) void partition_kernel(
    const int* __restrict__ src, const int* __restrict__ dst,
    int* __restrict__ bktcnt, uint* __restrict__ gpart, int E, int nbkt) {
  __shared__ uint staged[EPB];
  __shared__ ushort stagedb[EPB];     // bucket id per staged slot
  __shared__ int hist[NBKT_MAX];
  __shared__ int scanex[NBKT_MAX];
  __shared__ int lcur[NBKT_MAX];
  __shared__ int gbase[NBKT_MAX];
  __shared__ int s2[256];
  const int t = threadIdx.x;
  const int e0 = blockIdx.x * EPB;
  const int total = min(EPB, E - e0);

  hist[t] = 0; hist[t + 256] = 0;
  __syncthreads();

  int myb[16];
  uint myu[16];
#pragma unroll
  for (int q = 0; q < 16; ++q) {
    int e = e0 + q * 256 + t;
    if (e < E) {
      int s = src[e], d = dst[e];
      myb[q] = d >> 8;
      myu[q] = (uint)s | ((uint)(d & 255) << 24);
      atomicAdd(&hist[myb[q]], 1);
    } else {
      myb[q] = -1;
      myu[q] = 0;
    }
  }
  __syncthreads();

  int h0 = hist[2 * t], h1 = hist[2 * t + 1];
  s2[t] = h0 + h1;
  __syncthreads();
  for (int off = 1; off < 256; off <<= 1) {
    int v = (t >= off) ? s2[t - off] : 0;
    __syncthreads();
    s2[t] += v;
    __syncthreads();
  }
  int ex2 = s2[t] - (h0 + h1);
  scanex[2 * t] = ex2;
  scanex[2 * t + 1] = ex2 + h0;
  lcur[2 * t] = ex2;
  lcur[2 * t + 1] = ex2 + h0;
  __syncthreads();

#pragma unroll
  for (int q = 0; q < 2; ++q) {
    int b = t + q * 256;
    int c = hist[b];
    gbase[b] = (b < nbkt && c > 0)
                   ? (b * SLAB_CAP + atomicAdd(&bktcnt[b], c))
                   : 0;
  }

#pragma unroll
  for (int q = 0; q < 16; ++q) {
    if (myb[q] >= 0) {
      int p = atomicAdd(&lcur[myb[q]], 1);
      staged[p] = myu[q];
      stagedb[p] = (ushort)myb[q];
    }
  }
  __syncthreads();

  for (int i = t; i < total; i += 256) {
    int b = stagedb[i];
    gpart[gbase[b] + (i - scanex[b])] = staged[i];
  }
}

__global__ __launch_bounds__(512) void bucket_scan_kernel(
    const int* __restrict__ bktcnt, int* __restrict__ bucket_base,
    int* __restrict__ row_start, int nbkt, int n, int E) {
  __shared__ int sh[512];
  int t = threadIdx.x;
  int v = (t < nbkt) ? bktcnt[t] : 0;
  sh[t] = v;
  __syncthreads();
  for (int off = 1; off < 512; off <<= 1) {
    int u = (t >= off) ? sh[t - off] : 0;
    __syncthreads();
    sh[t] += u;
    __syncthreads();
  }
  if (t < nbkt) bucket_base[t] = sh[t] - v;
  if (t == 0) row_start[n] = E;
}

__global__ __launch_bounds__(256) void fine_fill_kernel(
    const uint* __restrict__ gpart, const int* __restrict__ bktcnt,
    const int* __restrict__ bucket_base, int* __restrict__ row_start,
    int* __restrict__ csr, int n) {
  __shared__ int hist[256];
  __shared__ int pfx[256];
  __shared__ int lcur[256];
  const int b = blockIdx.x;
  const int t = threadIdx.x;
  const int cnt = bktcnt[b];
  const uint* sl = gpart + (size_t)b * SLAB_CAP;
  hist[t] = 0;
  __syncthreads();
  for (int i = t; i < cnt; i += 256) atomicAdd(&hist[sl[i] >> 24], 1);
  __syncthreads();
  int h = hist[t];
  pfx[t] = h;
  __syncthreads();
  for (int off = 1; off < 256; off <<= 1) {
    int u = (t >= off) ? pfx[t - off] : 0;
    __syncthreads();
    pfx[t] += u;
    __syncthreads();
  }
  const int base = bucket_base[b] + pfx[t] - h;
  const int n0 = b << 8;
  if (n0 + t < n) row_start[n0 + t] = base;
  lcur[t] = base;
  __syncthreads();
  for (int i = t; i < cnt; i += 256) {
    uint u = sl[i];
    int p = atomicAdd(&lcur[u >> 24], 1);
    csr[p] = (int)(u & 0xFFFFFFu);
  }
}

// Half-wave (32 lanes) per node, int8 rows (128B each): lanes 0-15 load edge
// j (uint2 = 8 dims), lanes 16-31 edge j+1; masked scale sm = m*scale[src]
// folds dequant into fmaf; offset-128 removed once via csum correction;
// shfl_xor(16) cross-half reduce; bf16 row out.
__global__ __launch_bounds__(256) void aggregate_mean_i8_kernel(
    const uchar* __restrict__ hq, const float* __restrict__ scales,
    const int* __restrict__ csr, const int* __restrict__ row_start,
    ushort* __restrict__ outb, int n) {
  int node = (blockIdx.x * 256 + threadIdx.x) >> 5;
  int lane = threadIdx.x & 31;
  if (node >= n) return;
  const int sub = lane >> 4;       // edge parity handled by this lane
  const int dlo = (lane & 15) * 8; // dims dlo..dlo+7
  int e0 = row_start[node], e1 = row_start[node + 1];
  float a0 = 0.f, a1 = 0.f, a2 = 0.f, a3 = 0.f;
  float a4 = 0.f, a5 = 0.f, a6 = 0.f, a7 = 0.f;
  if (e1 > e0) {
    const int elast = e1 - 1;
    float csum = 0.f;
    for (int j0 = e0; j0 < e1; j0 += 8) {
      uint2 v[4];
      float sm[4];
#pragma unroll
      for (int q = 0; q < 4; ++q) {
        int j = j0 + 2 * q + sub;
        int jc = (j <= elast) ? j : elast;
        int s = csr[jc];
        v[q] = *(const uint2*)(hq + (size_t)s * 128 + dlo);
        float m = (j <= elast) ? 1.0f : 0.0f;
        sm[q] = m * scales[s];
      }
#pragma unroll
      for (int q = 0; q < 4; ++q) {
        const uint lo = v[q].x, hi = v[q].y;
        const float s_ = sm[q];
        a0 = fmaf((float)(lo & 255), s_, a0);
        a1 = fmaf((float)((lo >> 8) & 255), s_, a1);
        a2 = fmaf((float)((lo >> 16) & 255), s_, a2);
        a3 = fmaf((float)(lo >> 24), s_, a3);
        a4 = fmaf((float)(hi & 255), s_, a4);
        a5 = fmaf((float)((hi >> 8) & 255), s_, a5);
        a6 = fmaf((float)((hi >> 16) & 255), s_, a6);
        a7 = fmaf((float)(hi >> 24), s_, a7);
        csum += s_;
      }
    }
    const float c128 = 128.0f * csum;  // remove offset-128 bias
    a0 -= c128; a1 -= c128; a2 -= c128; a3 -= c128;
    a4 -= c128; a5 -= c128; a6 -= c128; a7 -= c128;
    a0 += __shfl_xor(a0, 16, 64);
    a1 += __shfl_xor(a1, 16, 64);
    a2 += __shfl_xor(a2, 16, 64);
    a3 += __shfl_xor(a3, 16, 64);
    a4 += __shfl_xor(a4, 16, 64);
    a5 += __shfl_xor(a5, 16, 64);
    a6 += __shfl_xor(a6, 16, 64);
    a7 += __shfl_xor(a7, 16, 64);
    float inv = 1.0f / (float)(e1 - e0);
    a0 *= inv; a1 *= inv; a2 *= inv; a3 *= inv;
    a4 *= inv; a5 *= inv; a6 *= inv; a7 *= inv;
  }
  if (lane < 16) {
    uint4 r;
    r.x = (uint)f2bf(a0) | ((uint)f2bf(a1) << 16);
    r.y = (uint)f2bf(a2) | ((uint)f2bf(a3) << 16);
    r.z = (uint)f2bf(a4) | ((uint)f2bf(a5) << 16);
    r.w = (uint)f2bf(a6) | ((uint)f2bf(a7) << 16);
    *(uint4*)(outb + (size_t)node * 128 + dlo) = r;
  }
}

// MFMA SAGE GEMM (R12 form): 64 nodes x 128 outs per block, 4 waves; wave w
// owns o-tiles {w, w+4} (B-frags in regs whole kernel). Single A buffer;
// __launch_bounds__(256,4) -> 4 waves/SIMD TLP hides load->MFMA dependency.
template <int RELU, int OUT_BF16>
__global__ __launch_bounds__(256, 4) void sage_gemm_mfma_kernel(
    const ushort* __restrict__ hs, const ushort* __restrict__ hn,
    const ushort* __restrict__ Wsb, const ushort* __restrict__ Wnb,
    const float* __restrict__ bias, void* __restrict__ out_, int n) {
  const int w = threadIdx.x >> 6;
  const int lane = threadIdx.x & 63;
  const int lr = lane & 15;
  const int lk = (lane >> 4) * 8;
  const int m0 = blockIdx.x * 64;
  if (m0 >= n) return;

  short8 bs[2][4], bn[2][4];
  float bv[2];
  int oc[2];
#pragma unroll
  for (int u = 0; u < 2; ++u) {
    oc[u] = (w + u * 4) * 16 + lr;
    const ushort* qs = Wsb + (size_t)oc[u] * 128 + lk;
    const ushort* qn = Wnb + (size_t)oc[u] * 128 + lk;
#pragma unroll
    for (int s = 0; s < 4; ++s) {
      bs[u][s] = *(const short8*)(qs + s * 32);
      bn[u][s] = *(const short8*)(qn + s * 32);
    }
    bv[u] = bias[oc[u]];
  }

  const int nmt = min(4, (n - m0 + 15) >> 4);
  for (int mt = 0; mt < nmt; ++mt) {
    short8 as[4], an[4];
    {
      int arow = m0 + mt * 16 + lr;
      if (arow >= n) arow = n - 1;
      const ushort* ps = hs + (size_t)arow * 128 + lk;
      const ushort* pq = hn + (size_t)arow * 128 + lk;
#pragma unroll
      for (int s = 0; s < 4; ++s) {
        as[s] = *(const short8*)(ps + s * 32);
        an[s] = *(const short8*)(pq + s * 32);
      }
    }
    const int mbase = m0 + mt * 16 + (lane >> 4) * 4;
#pragma unroll
    for (int u = 0; u < 2; ++u) {
      f32x4 acc = {0.f, 0.f, 0.f, 0.f};
#pragma unroll
      for (int s = 0; s < 4; ++s)
        acc = __builtin_amdgcn_mfma_f32_16x16x32_bf16(as[s], bs[u][s], acc, 0, 0, 0);
#pragma unroll
      for (int s = 0; s < 4; ++s)
        acc = __builtin_amdgcn_mfma_f32_16x16x32_bf16(an[s], bn[u][s], acc, 0, 0, 0);
#pragma unroll
      for (int r = 0; r < 4; ++r) {
        int node = mbase + r;
        if (node < n) {
          float v = acc[r] + bv[u];
          if (RELU) v = fmaxf(v, 0.f);
          if (OUT_BF16)
            ((ushort*)out_)[(size_t)node * 128 + oc[u]] = f2bf(v);
          else
            ((float*)out_)[(size_t)node * 128 + oc[u]] = v;
        }
      }
    }
  }
}

extern "C" void kernel_launch(void* const* d_in, const int* in_sizes, int n_in,
                              void* d_out, int out_size, void* d_ws, size_t ws_size,
                              hipStream_t stream) {
  const float* x   = (const float*)d_in[0];
  const int*   src = (const int*)d_in[1];
  const int*   dst = (const int*)d_in[2];
  const float* Ws1 = (const float*)d_in[3];
  const float* Wn1 = (const float*)d_in[4];
  const float* b1  = (const float*)d_in[5];
  const float* Ws2 = (const float*)d_in[6];
  const float* Wn2 = (const float*)d_in[7];
  const float* b2  = (const float*)d_in[8];
  float* out = (float*)d_out;
  const int D = 128;
  const int N = in_sizes[0] / D;
  const int E = in_sizes[1];
  (void)n_in; (void)out_size; (void)ws_size;

  char* p = (char*)d_ws;
  auto carve = [&](size_t bytes) {
    char* r = p;
    p += (bytes + 255) & ~(size_t)255;
    return r;
  };
  int*    bktcnt      = (int*)carve(NBKT_MAX * 4);
  int*    bucket_base = (int*)carve(NBKT_MAX * 4);
  int*    row_start   = (int*)carve((size_t)(N + 1) * 4);
  uint*   gpart       = (uint*)carve((size_t)NBKT_MAX * SLAB_CAP * 4);
  int*    csr         = (int*)carve((size_t)E * 4);
  ushort* xb          = (ushort*)carve((size_t)N * D * 2);
  ushort* h1b         = (ushort*)carve((size_t)N * D * 2);
  ushort* hnb         = (ushort*)carve((size_t)N * D * 2);
  float*  xs          = (float*)carve((size_t)N * 4);
  float*  h1s         = (float*)carve((size_t)N * 4);
  ushort* Wsb1        = (ushort*)carve((size_t)D * D * 2);
  ushort* Wnb1        = (ushort*)carve((size_t)D * D * 2);
  ushort* Wsb2        = (ushort*)carve((size_t)D * D * 2);
  ushort* Wnb2        = (ushort*)carve((size_t)D * D * 2);
  // Aliased int8 tables (no extra footprint):
  //   xq  overlays h1b : written at start, consumed by agg-1, then gemm-1
  //                      overwrites h1b (xq dead by then).
  //   h1q overlays xb  : written after gemm-1's last read of xb.
  uchar* xq  = (uchar*)h1b;
  uchar* h1q = (uchar*)xb;

  hipMemsetAsync(bktcnt, 0, NBKT_MAX * 4, stream);

  const int nbkt = (N + 255) >> 8;
  const int wq = D * D / 4;

  f32_to_bf16_kernel<<<(N * D / 4 + 255) / 256, 256, 0, stream>>>(x, xb, N * D / 4);
  {
    dim3 g((wq + 255) / 256, 4);
    w_to_bf16_kernel<<<g, 256, 0, stream>>>(Ws1, Wn1, Ws2, Wn2,
                                            Wsb1, Wnb1, Wsb2, Wnb2, wq);
  }
  quant_rows_kernel<1><<<(N + 7) / 8, 256, 0, stream>>>(x, xq, xs, N);

  partition_kernel<<<(E + EPB - 1) / EPB, 256, 0, stream>>>(src, dst, bktcnt, gpart, E, nbkt);
  bucket_scan_kernel<<<1, 512, 0, stream>>>(bktcnt, bucket_base, row_start, nbkt, N, E);
  fine_fill_kernel<<<nbkt, 256, 0, stream>>>(gpart, bktcnt, bucket_base, row_start, csr, N);

  const int gblocks = (N + 63) / 64;

  // Layer 1: int8 gather-mean -> bf16 hnb; MFMA GEMM (xb, hnb) -> bf16 h1
  aggregate_mean_i8_kernel<<<(N + 7) / 8, 256, 0, stream>>>(xq, xs, csr, row_start, hnb, N);
  sage_gemm_mfma_kernel<1, 1><<<gblocks, 256, 0, stream>>>(
      xb, hnb, Wsb1, Wnb1, b1, h1b, N);

  // Quantize h1 for layer-2 gather (h1q overlays xb, now dead)
  quant_rows_kernel<0><<<(N + 7) / 8, 256, 0, stream>>>(h1b, h1q, h1s, N);

  // Layer 2: int8 gather-mean -> bf16 hnb; MFMA GEMM (h1b, hnb) -> fp32 out
  aggregate_mean_i8_kernel<<<(N + 7) / 8, 256, 0, stream>>>(h1q, h1s, csr, row_start, hnb, N);
  sage_gemm_mfma_kernel<0, 0><<<gblocks, 256, 0, stream>>>(
      h1b, hnb, Wsb2, Wnb2, b2, out, N);
}

// Round 15
// 206.218 us; speedup vs baseline: 1.2126x; 1.1434x over previous
//
#include <hip/hip_runtime.h>

// ---------------------------------------------------------------------------
// GraphSAGE (2-layer, mean aggregator), N=100000, E=1600000, D=128, fp32 out.
// R14: MFMA-fragment-major layout for all GEMM operands. The ~45us GEMM was
// L1-transaction-bound: each A-fragment load touched 16 scattered 64B lines
// (rows 256B apart). Now A (x, h1, hn) and W are stored as
//   frag[tile=n>>4][s=k>>5][lane=(n&15)+((k>>3)&3)*16][8 elems]
// so a wave's fragment load is ONE contiguous 1KB read. int8 gather tables
// stay row-major (R13 win kept); final output stays row-major fp32.
// ---------------------------------------------------------------------------

typedef unsigned int uint;
typedef unsigned short ushort;
typedef unsigned char uchar;
using short8 = __attribute__((ext_vector_type(8))) short;
using f32x4  = __attribute__((ext_vector_type(4))) float;

__device__ __forceinline__ float bflo(uint u) { return __uint_as_float(u << 16); }
__device__ __forceinline__ float bfhi(uint u) { return __uint_as_float(u & 0xffff0000u); }
__device__ __forceinline__ ushort f2bf(float f) {
  uint u = __float_as_uint(f);
  return (ushort)((u + 0x7fffu + ((u >> 16) & 1u)) >> 16);
}

#define EPB 4096        // edges per partition block
#define NBKT_MAX 512    // buckets of 256 nodes; N<=131072
#define SLAB_CAP 5120   // slab capacity per bucket

// ---- fragment-major layout helpers (elements, bf16) -----------------------
// FIDX(n,k) = (n>>4)*2048 + (k>>5)*512 + (((k>>3)&3)*16 + (n&15))*8 + (k&7)

// fp32 row-major x -> fragment-major bf16. One block per 16-node tile;
// thread t = (s = t>>6, lane = t&63) writes 16B contiguous.
__global__ __launch_bounds__(256) void x_to_frag_kernel(
    const float* __restrict__ x, ushort* __restrict__ xf, int n) {
  const int tile = blockIdx.x;
  const int s = threadIdx.x >> 6;
  const int l = threadIdx.x & 63;
  const int row = tile * 16 + (l & 15);
  const int k = s * 32 + (l >> 4) * 8;
  ushort4 r0 = {0, 0, 0, 0}, r1 = {0, 0, 0, 0};
  if (row < n) {
    const float* p = x + (size_t)row * 128 + k;
    float4 a = ((const float4*)p)[0];
    float4 b = ((const float4*)p)[1];
    r0.x = f2bf(a.x); r0.y = f2bf(a.y); r0.z = f2bf(a.z); r0.w = f2bf(a.w);
    r1.x = f2bf(b.x); r1.y = f2bf(b.y); r1.z = f2bf(b.z); r1.w = f2bf(b.w);
  }
  ushort* dp = xf + (size_t)tile * 2048 + s * 512 + l * 8;
  *(ushort4*)dp = r0;
  *(ushort4*)(dp + 4) = r1;
}

// 4 weight matrices fp32 [128][128] -> fragment-major bf16.
// grid (8 o-tiles, 4 matrices), 256 threads.
__global__ __launch_bounds__(256) void w_to_frag_kernel(
    const float* __restrict__ w0, const float* __restrict__ w1,
    const float* __restrict__ w2, const float* __restrict__ w3,
    ushort* __restrict__ o0, ushort* __restrict__ o1,
    ushort* __restrict__ o2, ushort* __restrict__ o3) {
  const float* in = (blockIdx.y == 0) ? w0 : (blockIdx.y == 1) ? w1
                    : (blockIdx.y == 2) ? w2 : w3;
  ushort* out = (blockIdx.y == 0) ? o0 : (blockIdx.y == 1) ? o1
                : (blockIdx.y == 2) ? o2 : o3;
  const int tile = blockIdx.x;
  const int s = threadIdx.x >> 6;
  const int l = threadIdx.x & 63;
  const int row = tile * 16 + (l & 15);
  const int k = s * 32 + (l >> 4) * 8;
  const float* p = in + (size_t)row * 128 + k;
  float4 a = ((const float4*)p)[0];
  float4 b = ((const float4*)p)[1];
  ushort4 r0, r1;
  r0.x = f2bf(a.x); r0.y = f2bf(a.y); r0.z = f2bf(a.z); r0.w = f2bf(a.w);
  r1.x = f2bf(b.x); r1.y = f2bf(b.y); r1.z = f2bf(b.z); r1.w = f2bf(b.w);
  ushort* dp = out + (size_t)tile * 2048 + s * 512 + l * 8;
  *(ushort4*)dp = r0;
  *(ushort4*)(dp + 4) = r1;
}

// Per-row symmetric int8 quantization (offset-128 unsigned storage).
// Half-wave (32 lanes) per node; lane holds dims lane*4..lane*4+3.
// IN_F32=1: row-major fp32 input; IN_F32=0: fragment-major bf16 input.
template <int IN_F32>
__global__ __launch_bounds__(256) void quant_rows_kernel(
    const void* __restrict__ in_, uchar* __restrict__ outq,
    float* __restrict__ scales, int n) {
  int node = (blockIdx.x * 256 + threadIdx.x) >> 5;
  int lane = threadIdx.x & 31;
  if (node >= n) return;
  float f[4];
  if (IN_F32) {
    float4 v = *(const float4*)((const float*)in_ + (size_t)node * 128 + lane * 4);
    f[0] = v.x; f[1] = v.y; f[2] = v.z; f[3] = v.w;
  } else {
    // frag addr for (node, k=lane*4): 8B load
    const ushort* hp = (const ushort*)in_ + (size_t)(node >> 4) * 2048 +
                       (lane >> 3) * 512 +
                       (((lane >> 1) & 3) * 16 + (node & 15)) * 8 +
                       (lane & 1) * 4;
    uint2 v = *(const uint2*)hp;
    f[0] = bflo(v.x); f[1] = bfhi(v.x); f[2] = bflo(v.y); f[3] = bfhi(v.y);
  }
  float mx = fmaxf(fmaxf(fabsf(f[0]), fabsf(f[1])),
                   fmaxf(fabsf(f[2]), fabsf(f[3])));
#pragma unroll
  for (int off = 1; off < 32; off <<= 1) mx = fmaxf(mx, __shfl_xor(mx, off, 64));
  float inv = (mx > 0.f) ? 127.0f / mx : 0.f;
  uint q0 = (uint)(__float2int_rn(f[0] * inv) + 128);
  uint q1 = (uint)(__float2int_rn(f[1] * inv) + 128);
  uint q2 = (uint)(__float2int_rn(f[2] * inv) + 128);
  uint q3 = (uint)(__float2int_rn(f[3] * inv) + 128);
  uint packed = q0 | (q1 << 8) | (q2 << 16) | (q3 << 24);
  *(uint*)(outq + (size_t)node * 128 + lane * 4) = packed;
  if (lane == 0) scales[node] = (mx > 0.f) ? mx / 127.0f : 0.f;
}

__global__ __launch_bounds__(256) void partition_kernel(
    const int* __restrict__ src, const int* __restrict__ dst,
    int* __restrict__ bktcnt, uint* __restrict__ gpart, int E, int nbkt) {
  __shared__ uint staged[EPB];
  __shared__ ushort stagedb[EPB];
  __shared__ int hist[NBKT_MAX];
  __shared__ int scanex[NBKT_MAX];
  __shared__ int lcur[NBKT_MAX];
  __shared__ int gbase[NBKT_MAX];
  __shared__ int s2[256];
  const int t = threadIdx.x;
  const int e0 = blockIdx.x * EPB;
  const int total = min(EPB, E - e0);

  hist[t] = 0; hist[t + 256] = 0;
  __syncthreads();

  int myb[16];
  uint myu[16];
#pragma unroll
  for (int q = 0; q < 16; ++q) {
    int e = e0 + q * 256 + t;
    if (e < E) {
      int s = src[e], d = dst[e];
      myb[q] = d >> 8;
      myu[q] = (uint)s | ((uint)(d & 255) << 24);
      atomicAdd(&hist[myb[q]], 1);
    } else {
      myb[q] = -1;
      myu[q] = 0;
    }
  }
  __syncthreads();

  int h0 = hist[2 * t], h1 = hist[2 * t + 1];
  s2[t] = h0 + h1;
  __syncthreads();
  for (int off = 1; off < 256; off <<= 1) {
    int v = (t >= off) ? s2[t - off] : 0;
    __syncthreads();
    s2[t] += v;
    __syncthreads();
  }
  int ex2 = s2[t] - (h0 + h1);
  scanex[2 * t] = ex2;
  scanex[2 * t + 1] = ex2 + h0;
  lcur[2 * t] = ex2;
  lcur[2 * t + 1] = ex2 + h0;
  __syncthreads();

#pragma unroll
  for (int q = 0; q < 2; ++q) {
    int b = t + q * 256;
    int c = hist[b];
    gbase[b] = (b < nbkt && c > 0)
                   ? (b * SLAB_CAP + atomicAdd(&bktcnt[b], c))
                   : 0;
  }

#pragma unroll
  for (int q = 0; q < 16; ++q) {
    if (myb[q] >= 0) {
      int p = atomicAdd(&lcur[myb[q]], 1);
      staged[p] = myu[q];
      stagedb[p] = (ushort)myb[q];
    }
  }
  __syncthreads();

  for (int i = t; i < total; i += 256) {
    int b = stagedb[i];
    gpart[gbase[b] + (i - scanex[b])] = staged[i];
  }
}

__global__ __launch_bounds__(512) void bucket_scan_kernel(
    const int* __restrict__ bktcnt, int* __restrict__ bucket_base,
    int* __restrict__ row_start, int nbkt, int n, int E) {
  __shared__ int sh[512];
  int t = threadIdx.x;
  int v = (t < nbkt) ? bktcnt[t] : 0;
  sh[t] = v;
  __syncthreads();
  for (int off = 1; off < 512; off <<= 1) {
    int u = (t >= off) ? sh[t - off] : 0;
    __syncthreads();
    sh[t] += u;
    __syncthreads();
  }
  if (t < nbkt) bucket_base[t] = sh[t] - v;
  if (t == 0) row_start[n] = E;
}

__global__ __launch_bounds__(256) void fine_fill_kernel(
    const uint* __restrict__ gpart, const int* __restrict__ bktcnt,
    const int* __restrict__ bucket_base, int* __restrict__ row_start,
    int* __restrict__ csr, int n) {
  __shared__ int hist[256];
  __shared__ int pfx[256];
  __shared__ int lcur[256];
  const int b = blockIdx.x;
  const int t = threadIdx.x;
  const int cnt = bktcnt[b];
  const uint* sl = gpart + (size_t)b * SLAB_CAP;
  hist[t] = 0;
  __syncthreads();
  for (int i = t; i < cnt; i += 256) atomicAdd(&hist[sl[i] >> 24], 1);
  __syncthreads();
  int h = hist[t];
  pfx[t] = h;
  __syncthreads();
  for (int off = 1; off < 256; off <<= 1) {
    int u = (t >= off) ? pfx[t - off] : 0;
    __syncthreads();
    pfx[t] += u;
    __syncthreads();
  }
  const int base = bucket_base[b] + pfx[t] - h;
  const int n0 = b << 8;
  if (n0 + t < n) row_start[n0 + t] = base;
  lcur[t] = base;
  __syncthreads();
  for (int i = t; i < cnt; i += 256) {
    uint u = sl[i];
    int p = atomicAdd(&lcur[u >> 24], 1);
    csr[p] = (int)(u & 0xFFFFFFu);
  }
}

// Half-wave (32 lanes) per node, int8 rows (row-major, 128B): paired gather
// (lanes 0-15 edge j, 16-31 edge j+1), dequant folded into fmaf + offset
// correction; OUTPUT written in fragment-major bf16 (16B/lane, new address).
__global__ __launch_bounds__(256) void aggregate_mean_i8_kernel(
    const uchar* __restrict__ hq, const float* __restrict__ scales,
    const int* __restrict__ csr, const int* __restrict__ row_start,
    ushort* __restrict__ outf, int n) {
  int node = (blockIdx.x * 256 + threadIdx.x) >> 5;
  int lane = threadIdx.x & 31;
  if (node >= n) return;
  const int sub = lane >> 4;
  const int dlo = (lane & 15) * 8;
  int e0 = row_start[node], e1 = row_start[node + 1];
  float a0 = 0.f, a1 = 0.f, a2 = 0.f, a3 = 0.f;
  float a4 = 0.f, a5 = 0.f, a6 = 0.f, a7 = 0.f;
  if (e1 > e0) {
    const int elast = e1 - 1;
    float csum = 0.f;
    for (int j0 = e0; j0 < e1; j0 += 8) {
      uint2 v[4];
      float sm[4];
#pragma unroll
      for (int q = 0; q < 4; ++q) {
        int j = j0 + 2 * q + sub;
        int jc = (j <= elast) ? j : elast;
        int s = csr[jc];
        v[q] = *(const uint2*)(hq + (size_t)s * 128 + dlo);
        float m = (j <= elast) ? 1.0f : 0.0f;
        sm[q] = m * scales[s];
      }
#pragma unroll
      for (int q = 0; q < 4; ++q) {
        const uint lo = v[q].x, hi = v[q].y;
        const float s_ = sm[q];
        a0 = fmaf((float)(lo & 255), s_, a0);
        a1 = fmaf((float)((lo >> 8) & 255), s_, a1);
        a2 = fmaf((float)((lo >> 16) & 255), s_, a2);
        a3 = fmaf((float)(lo >> 24), s_, a3);
        a4 = fmaf((float)(hi & 255), s_, a4);
        a5 = fmaf((float)((hi >> 8) & 255), s_, a5);
        a6 = fmaf((float)((hi >> 16) & 255), s_, a6);
        a7 = fmaf((float)(hi >> 24), s_, a7);
        csum += s_;
      }
    }
    const float c128 = 128.0f * csum;
    a0 -= c128; a1 -= c128; a2 -= c128; a3 -= c128;
    a4 -= c128; a5 -= c128; a6 -= c128; a7 -= c128;
    a0 += __shfl_xor(a0, 16, 64);
    a1 += __shfl_xor(a1, 16, 64);
    a2 += __shfl_xor(a2, 16, 64);
    a3 += __shfl_xor(a3, 16, 64);
    a4 += __shfl_xor(a4, 16, 64);
    a5 += __shfl_xor(a5, 16, 64);
    a6 += __shfl_xor(a6, 16, 64);
    a7 += __shfl_xor(a7, 16, 64);
    float inv = 1.0f / (float)(e1 - e0);
    a0 *= inv; a1 *= inv; a2 *= inv; a3 *= inv;
    a4 *= inv; a5 *= inv; a6 *= inv; a7 *= inv;
  }
  if (lane < 16) {
    uint4 r;
    r.x = (uint)f2bf(a0) | ((uint)f2bf(a1) << 16);
    r.y = (uint)f2bf(a2) | ((uint)f2bf(a3) << 16);
    r.z = (uint)f2bf(a4) | ((uint)f2bf(a5) << 16);
    r.w = (uint)f2bf(a6) | ((uint)f2bf(a7) << 16);
    // frag addr for (node, k=lane*8): s=lane>>2, chunk=lane&3
    ushort* dp = outf + (size_t)(node >> 4) * 2048 + (lane >> 2) * 512 +
                 ((lane & 3) * 16 + (node & 15)) * 8;
    *(uint4*)dp = r;
  }
}

// MFMA SAGE GEMM v5 (fragment-major operands): 64 nodes x 128 outs per
// block, 4 waves; wave w owns o-tiles {w, w+4}. ALL fragment loads are
// contiguous 1KB per wave (was 16 scattered lines per load).
// OUT_FRAG=1: write bf16 fragment-major; else fp32 row-major.
template <int RELU, int OUT_FRAG>
__global__ __launch_bounds__(256, 4) void sage_gemm_mfma_kernel(
    const ushort* __restrict__ hs, const ushort* __restrict__ hn,
    const ushort* __restrict__ Wsf, const ushort* __restrict__ Wnf,
    const float* __restrict__ bias, void* __restrict__ out_, int n) {
  const int w = threadIdx.x >> 6;
  const int lane = threadIdx.x & 63;
  const int lr = lane & 15;
  const int m0 = blockIdx.x * 64;
  if (m0 >= n) return;

  short8 bs[2][4], bn[2][4];
  float bv[2];
#pragma unroll
  for (int u = 0; u < 2; ++u) {
    const int ot = w + u * 4;
    const ushort* qs = Wsf + (size_t)ot * 2048 + lane * 8;
    const ushort* qn = Wnf + (size_t)ot * 2048 + lane * 8;
#pragma unroll
    for (int s = 0; s < 4; ++s) {
      bs[u][s] = *(const short8*)(qs + s * 512);
      bn[u][s] = *(const short8*)(qn + s * 512);
    }
    bv[u] = bias[ot * 16 + lr];
  }

  const int nmt = min(4, (n - m0 + 15) >> 4);
  for (int mt = 0; mt < nmt; ++mt) {
    const int tile = (m0 >> 4) + mt;
    short8 as[4], an[4];
    {
      const ushort* ps = hs + (size_t)tile * 2048 + lane * 8;
      const ushort* pq = hn + (size_t)tile * 2048 + lane * 8;
#pragma unroll
      for (int s = 0; s < 4; ++s) {
        as[s] = *(const short8*)(ps + s * 512);
        an[s] = *(const short8*)(pq + s * 512);
      }
    }
    const int rbase = (lane >> 4) * 4;        // node&15 base for this lane
    const int mbase = m0 + mt * 16 + rbase;   // global node base
#pragma unroll
    for (int u = 0; u < 2; ++u) {
      f32x4 acc = {0.f, 0.f, 0.f, 0.f};
#pragma unroll
      for (int s = 0; s < 4; ++s)
        acc = __builtin_amdgcn_mfma_f32_16x16x32_bf16(as[s], bs[u][s], acc, 0, 0, 0);
#pragma unroll
      for (int s = 0; s < 4; ++s)
        acc = __builtin_amdgcn_mfma_f32_16x16x32_bf16(an[s], bn[u][s], acc, 0, 0, 0);
      const int ot = w + u * 4;
      // frag C-write constant part for (k=oc=ot*16+lr)
      const size_t cu = (size_t)(ot >> 1) * 512 +
                        (((ot & 1) * 2 + (lr >> 3)) * 16) * 8 + (lr & 7);
#pragma unroll
      for (int r = 0; r < 4; ++r) {
        int node = mbase + r;
        if (node < n) {
          float v = acc[r] + bv[u];
          if (RELU) v = fmaxf(v, 0.f);
          if (OUT_FRAG) {
            ((ushort*)out_)[(size_t)tile * 2048 + (rbase + r) * 8 + cu] = f2bf(v);
          } else {
            ((float*)out_)[(size_t)node * 128 + ot * 16 + lr] = v;
          }
        }
      }
    }
  }
}

extern "C" void kernel_launch(void* const* d_in, const int* in_sizes, int n_in,
                              void* d_out, int out_size, void* d_ws, size_t ws_size,
                              hipStream_t stream) {
  const float* x   = (const float*)d_in[0];
  const int*   src = (const int*)d_in[1];
  const int*   dst = (const int*)d_in[2];
  const float* Ws1 = (const float*)d_in[3];
  const float* Wn1 = (const float*)d_in[4];
  const float* b1  = (const float*)d_in[5];
  const float* Ws2 = (const float*)d_in[6];
  const float* Wn2 = (const float*)d_in[7];
  const float* b2  = (const float*)d_in[8];
  float* out = (float*)d_out;
  const int D = 128;
  const int N = in_sizes[0] / D;
  const int E = in_sizes[1];
  (void)n_in; (void)out_size; (void)ws_size;

  const int tiles = (N + 15) >> 4;

  char* p = (char*)d_ws;
  auto carve = [&](size_t bytes) {
    char* r = p;
    p += (bytes + 255) & ~(size_t)255;
    return r;
  };
  int*    bktcnt      = (int*)carve(NBKT_MAX * 4);
  int*    bucket_base = (int*)carve(NBKT_MAX * 4);
  int*    row_start   = (int*)carve((size_t)(N + 1) * 4);
  uint*   gpart       = (uint*)carve((size_t)NBKT_MAX * SLAB_CAP * 4);
  int*    csr         = (int*)carve((size_t)E * 4);
  ushort* xbf         = (ushort*)carve((size_t)tiles * 2048 * 2);  // frag x
  ushort* h1f         = (ushort*)carve((size_t)tiles * 2048 * 2);  // frag h1
  ushort* hnf         = (ushort*)carve((size_t)tiles * 2048 * 2);  // frag mean
  float*  xs          = (float*)carve((size_t)N * 4);
  float*  h1s         = (float*)carve((size_t)N * 4);
  ushort* Wf1s        = (ushort*)carve((size_t)D * D * 2);
  ushort* Wf1n        = (ushort*)carve((size_t)D * D * 2);
  ushort* Wf2s        = (ushort*)carve((size_t)D * D * 2);
  ushort* Wf2n        = (ushort*)carve((size_t)D * D * 2);
  // Aliased int8 gather tables (row-major, 128B/node):
  //   xq  overlays h1f (dead until gemm1 writes it)
  //   h1q overlays xbf (dead after gemm1 reads it)
  uchar* xq  = (uchar*)h1f;
  uchar* h1q = (uchar*)xbf;

  hipMemsetAsync(bktcnt, 0, NBKT_MAX * 4, stream);

  const int nbkt = (N + 255) >> 8;

  x_to_frag_kernel<<<tiles, 256, 0, stream>>>(x, xbf, N);
  {
    dim3 g(8, 4);
    w_to_frag_kernel<<<g, 256, 0, stream>>>(Ws1, Wn1, Ws2, Wn2,
                                            Wf1s, Wf1n, Wf2s, Wf2n);
  }
  quant_rows_kernel<1><<<(N + 7) / 8, 256, 0, stream>>>(x, xq, xs, N);

  partition_kernel<<<(E + EPB - 1) / EPB, 256, 0, stream>>>(src, dst, bktcnt, gpart, E, nbkt);
  bucket_scan_kernel<<<1, 512, 0, stream>>>(bktcnt, bucket_base, row_start, nbkt, N, E);
  fine_fill_kernel<<<nbkt, 256, 0, stream>>>(gpart, bktcnt, bucket_base, row_start, csr, N);

  const int gblocks = (N + 63) / 64;

  // Layer 1: int8 gather-mean -> frag hnf; GEMM (xbf, hnf) -> frag h1f (+relu)
  aggregate_mean_i8_kernel<<<(N + 7) / 8, 256, 0, stream>>>(xq, xs, csr, row_start, hnf, N);
  sage_gemm_mfma_kernel<1, 1><<<gblocks, 256, 0, stream>>>(
      xbf, hnf, Wf1s, Wf1n, b1, h1f, N);

  // Quantize h1 (frag in, row-major int8 out; h1q overlays xbf, now dead)
  quant_rows_kernel<0><<<(N + 7) / 8, 256, 0, stream>>>(h1f, h1q, h1s, N);

  // Layer 2: int8 gather-mean -> frag hnf; GEMM (h1f, hnf) -> fp32 row out
  aggregate_mean_i8_kernel<<<(N + 7) / 8, 256, 0, stream>>>(h1q, h1s, csr, row_start, hnf, N);
  sage_gemm_mfma_kernel<0, 0><<<gblocks, 256, 0, stream>>>(
      h1f, hnf, Wf2s, Wf2n, b2, out, N);
}